// Round 1
// baseline (1040.621 us; speedup 1.0000x reference)
//
#include <hip/hip_runtime.h>
#include <math.h>

#define NHEAD 12
#define HD    64
#define SEQ   2048
#define BATCH 2
#define DM    768

__device__ __forceinline__ float dot4(float4 a, float4 b) {
    return a.x*b.x + a.y*b.y + a.z*b.z + a.w*b.w;
}

// ---------------------------------------------------------------------------
// QKV projection: Y = X @ W^T.  X [4096, 768] row-major, W [768, 768] row-major
// (Linear weight [out,in]).  Output written directly in [B, H, S, hd] layout.
// blockIdx.z selects {Wq->Q, Wk->K, Wv->V}.
// Tile 64x64, BK=16, 256 threads, 4x4 per thread.
// ---------------------------------------------------------------------------
__global__ __launch_bounds__(256)
void qkv_gemm(const float* __restrict__ X,
              const float* __restrict__ Wq, const float* __restrict__ Wk,
              const float* __restrict__ Wv,
              float* __restrict__ Q, float* __restrict__ K, float* __restrict__ V)
{
    const int m0 = blockIdx.x * 64;
    const int n0 = blockIdx.y * 64;
    const float* W = (blockIdx.z == 0) ? Wq : (blockIdx.z == 1) ? Wk : Wv;
    float*       Y = (blockIdx.z == 0) ? Q  : (blockIdx.z == 1) ? K  : V;

    // k-major LDS tiles; pad 68 (mult of 4 keeps float4 alignment; 2-way bank
    // aliasing only, which is free on CDNA4 [m136]).
    __shared__ __align__(16) float As[16][68];
    __shared__ __align__(16) float Bs[16][68];

    const int tid = threadIdx.x;
    const int tx = tid & 15, ty = tid >> 4;
    const int lm = tid >> 2;          // 0..63 : row within tile being loaded
    const int lk = (tid & 3) << 2;    // 0,4,8,12 : k offset

    const float* xrow = X + (size_t)(m0 + lm) * DM;
    const float* wrow = W + (size_t)(n0 + lm) * DM;

    float c[4][4] = {};

    for (int k0 = 0; k0 < DM; k0 += 16) {
        float4 av = *(const float4*)(xrow + k0 + lk);
        float4 bv = *(const float4*)(wrow + k0 + lk);
        __syncthreads();                       // prev compute done reading LDS
        As[lk+0][lm] = av.x; As[lk+1][lm] = av.y; As[lk+2][lm] = av.z; As[lk+3][lm] = av.w;
        Bs[lk+0][lm] = bv.x; Bs[lk+1][lm] = bv.y; Bs[lk+2][lm] = bv.z; Bs[lk+3][lm] = bv.w;
        __syncthreads();
        #pragma unroll
        for (int kk = 0; kk < 16; ++kk) {
            float4 a4 = *(const float4*)&As[kk][ty << 2];
            float4 b4 = *(const float4*)&Bs[kk][tx << 2];
            float a[4] = {a4.x, a4.y, a4.z, a4.w};
            float b[4] = {b4.x, b4.y, b4.z, b4.w};
            #pragma unroll
            for (int i = 0; i < 4; ++i)
                #pragma unroll
                for (int j = 0; j < 4; ++j)
                    c[i][j] = fmaf(a[i], b[j], c[i][j]);
        }
    }

    // n-block index == head index (64-wide heads, n0 multiple of 64)
    const int h = blockIdx.y;
    #pragma unroll
    for (int i = 0; i < 4; ++i) {
        int m = m0 + (ty << 2) + i;
        int b = m >> 11;        // / 2048
        int s = m & 2047;
        float4 o = make_float4(c[i][0], c[i][1], c[i][2], c[i][3]);
        *(float4*)&Y[(((size_t)b * NHEAD + h) * SEQ + s) * HD + (tx << 2)] = o;
    }
}

// ---------------------------------------------------------------------------
// Flash-style causal attention, fp32.  One block = 64 q-rows of one (b,h).
// 256 threads as 16x16; each thread owns a 4(row)x4 slice of the 64x64 score
// tile and a 4(row)x4(dim) slice of the O accumulator.
// K and V time-share one LDS buffer (load K -> scores -> load V -> PV).
// ---------------------------------------------------------------------------
__global__ __launch_bounds__(256)
void attn_fwd(const float* __restrict__ Q, const float* __restrict__ K,
              const float* __restrict__ V, float* __restrict__ O)
{
    const int qt = blockIdx.x;           // 0..31
    const int bh = blockIdx.y;           // 0..23
    const size_t base = (size_t)bh * SEQ * HD;
    const float* Qb = Q + base;
    const float* Kb = K + base;
    const float* Vb = V + base;
    float*       Ob = O + base;

    __shared__ __align__(16) float Qs [64][68];
    __shared__ __align__(16) float KVs[64][68];
    __shared__ __align__(16) float Ps [64][68];

    const int tid = threadIdx.x;
    const int tx = tid & 15, ty = tid >> 4;
    const int lr = tid >> 2;          // 0..63 : row loaded by this thread
    const int lc = (tid & 3) << 4;    // 0,16,32,48 : col base (16 floats each)

    const int q0 = qt * 64;

    // Load Q tile, pre-scaled by 1/sqrt(hd) = 1/8.
    {
        const float* src = Qb + (size_t)(q0 + lr) * HD + lc;
        #pragma unroll
        for (int j = 0; j < 4; ++j) {
            float4 v = *(const float4*)(src + 4*j);
            v.x *= 0.125f; v.y *= 0.125f; v.z *= 0.125f; v.w *= 0.125f;
            *(float4*)&Qs[lr][lc + 4*j] = v;
        }
    }

    float  m_r[4], l_r[4];
    float4 oa[4];
    #pragma unroll
    for (int i = 0; i < 4; ++i) {
        m_r[i] = -INFINITY; l_r[i] = 0.f;
        oa[i] = make_float4(0.f, 0.f, 0.f, 0.f);
    }

    for (int kt = 0; kt <= qt; ++kt) {
        const int k0 = kt * 64;

        __syncthreads();              // prev PV done reading KVs/Ps
        {
            const float* src = Kb + (size_t)(k0 + lr) * HD + lc;
            #pragma unroll
            for (int j = 0; j < 4; ++j)
                *(float4*)&KVs[lr][lc + 4*j] = *(const float4*)(src + 4*j);
        }
        __syncthreads();              // K tile (and Q on iter 0) visible

        // scores: sc[i][j] = (q/8) . k   over 64 dims
        float sc[4][4] = {};
        #pragma unroll
        for (int d4 = 0; d4 < 16; ++d4) {
            float4 q4[4], k4[4];
            #pragma unroll
            for (int i = 0; i < 4; ++i) q4[i] = *(const float4*)&Qs [(ty<<2)+i][d4<<2];
            #pragma unroll
            for (int j = 0; j < 4; ++j) k4[j] = *(const float4*)&KVs[(tx<<2)+j][d4<<2];
            #pragma unroll
            for (int i = 0; i < 4; ++i)
                #pragma unroll
                for (int j = 0; j < 4; ++j)
                    sc[i][j] += dot4(q4[i], k4[j]);
        }

        if (kt == qt) {               // causal mask on the diagonal tile
            #pragma unroll
            for (int i = 0; i < 4; ++i) {
                int qrow = (ty << 2) + i;
                #pragma unroll
                for (int j = 0; j < 4; ++j)
                    if (((tx << 2) + j) > qrow) sc[i][j] = -INFINITY;
            }
        }

        // online softmax (rows split across the 16 tx lanes of each ty group)
        float fac[4];
        #pragma unroll
        for (int i = 0; i < 4; ++i) {
            float rmax = fmaxf(fmaxf(sc[i][0], sc[i][1]), fmaxf(sc[i][2], sc[i][3]));
            #pragma unroll
            for (int off = 1; off < 16; off <<= 1)
                rmax = fmaxf(rmax, __shfl_xor(rmax, off));
            float mn = fmaxf(m_r[i], rmax);
            fac[i] = __expf(m_r[i] - mn);      // exp(-inf)=0 on first tile
            m_r[i] = mn;
            float rsum = 0.f;
            #pragma unroll
            for (int j = 0; j < 4; ++j) {
                float p = __expf(sc[i][j] - mn);
                sc[i][j] = p;
                rsum += p;
            }
            #pragma unroll
            for (int off = 1; off < 16; off <<= 1)
                rsum += __shfl_xor(rsum, off);
            l_r[i] = l_r[i] * fac[i] + rsum;
        }

        // publish P, rescale O accumulator
        #pragma unroll
        for (int i = 0; i < 4; ++i) {
            *(float4*)&Ps[(ty<<2)+i][tx<<2] =
                make_float4(sc[i][0], sc[i][1], sc[i][2], sc[i][3]);
            oa[i].x *= fac[i]; oa[i].y *= fac[i];
            oa[i].z *= fac[i]; oa[i].w *= fac[i];
        }

        __syncthreads();              // all score reads of KVs(K) + P writes done
        {
            const float* src = Vb + (size_t)(k0 + lr) * HD + lc;
            #pragma unroll
            for (int j = 0; j < 4; ++j)
                *(float4*)&KVs[lr][lc + 4*j] = *(const float4*)(src + 4*j);
        }
        __syncthreads();              // V tile visible

        // O += P @ V
        #pragma unroll
        for (int j4 = 0; j4 < 16; ++j4) {
            float4 p4[4], v4[4];
            #pragma unroll
            for (int i = 0; i < 4; ++i)  p4[i]  = *(const float4*)&Ps [(ty<<2)+i][j4<<2];
            #pragma unroll
            for (int jj = 0; jj < 4; ++jj) v4[jj] = *(const float4*)&KVs[(j4<<2)+jj][tx<<2];
            #pragma unroll
            for (int i = 0; i < 4; ++i) {
                oa[i].x += p4[i].x*v4[0].x + p4[i].y*v4[1].x + p4[i].z*v4[2].x + p4[i].w*v4[3].x;
                oa[i].y += p4[i].x*v4[0].y + p4[i].y*v4[1].y + p4[i].z*v4[2].y + p4[i].w*v4[3].y;
                oa[i].z += p4[i].x*v4[0].z + p4[i].y*v4[1].z + p4[i].z*v4[2].z + p4[i].w*v4[3].z;
                oa[i].w += p4[i].x*v4[0].w + p4[i].y*v4[1].w + p4[i].z*v4[2].w + p4[i].w*v4[3].w;
            }
        }
    }

    #pragma unroll
    for (int i = 0; i < 4; ++i) {
        float inv = 1.0f / l_r[i];
        float4 r = make_float4(oa[i].x*inv, oa[i].y*inv, oa[i].z*inv, oa[i].w*inv);
        *(float4*)&Ob[(size_t)(q0 + (ty << 2) + i) * HD + (tx << 2)] = r;
    }
}

// ---------------------------------------------------------------------------
// Output projection: out = O_mat @ Wo^T,  O_mat[m, k] gathered from [B,H,S,hd]
// (m = b*S+s, k = h*64+d).  Same 64x64 tile GEMM as qkv_gemm.
// ---------------------------------------------------------------------------
__global__ __launch_bounds__(256)
void out_gemm(const float* __restrict__ O, const float* __restrict__ Wo,
              float* __restrict__ Yout)
{
    const int m0 = blockIdx.x * 64;
    const int n0 = blockIdx.y * 64;

    __shared__ __align__(16) float As[16][68];
    __shared__ __align__(16) float Bs[16][68];

    const int tid = threadIdx.x;
    const int tx = tid & 15, ty = tid >> 4;
    const int lm = tid >> 2;
    const int lk = (tid & 3) << 2;

    const int m = m0 + lm;
    const int b = m >> 11;
    const int s = m & 2047;
    const float* wrow = Wo + (size_t)(n0 + lm) * DM;

    float c[4][4] = {};

    for (int k0 = 0; k0 < DM; k0 += 16) {
        int k  = k0 + lk;
        int hh = k >> 6;
        int d  = k & 63;
        float4 av = *(const float4*)&O[(((size_t)b * NHEAD + hh) * SEQ + s) * HD + d];
        float4 bv = *(const float4*)(wrow + k);
        __syncthreads();
        As[lk+0][lm] = av.x; As[lk+1][lm] = av.y; As[lk+2][lm] = av.z; As[lk+3][lm] = av.w;
        Bs[lk+0][lm] = bv.x; Bs[lk+1][lm] = bv.y; Bs[lk+2][lm] = bv.z; Bs[lk+3][lm] = bv.w;
        __syncthreads();
        #pragma unroll
        for (int kk = 0; kk < 16; ++kk) {
            float4 a4 = *(const float4*)&As[kk][ty << 2];
            float4 b4 = *(const float4*)&Bs[kk][tx << 2];
            float a[4] = {a4.x, a4.y, a4.z, a4.w};
            float bb[4] = {b4.x, b4.y, b4.z, b4.w};
            #pragma unroll
            for (int i = 0; i < 4; ++i)
                #pragma unroll
                for (int j = 0; j < 4; ++j)
                    c[i][j] = fmaf(a[i], bb[j], c[i][j]);
        }
    }

    #pragma unroll
    for (int i = 0; i < 4; ++i) {
        int mm = m0 + (ty << 2) + i;
        float4 o = make_float4(c[i][0], c[i][1], c[i][2], c[i][3]);
        *(float4*)&Yout[(size_t)mm * DM + n0 + (tx << 2)] = o;
    }
}

// ---------------------------------------------------------------------------
extern "C" void kernel_launch(void* const* d_in, const int* in_sizes, int n_in,
                              void* d_out, int out_size, void* d_ws, size_t ws_size,
                              hipStream_t stream)
{
    const float* x  = (const float*)d_in[0];
    const float* Wq = (const float*)d_in[1];
    const float* Wk = (const float*)d_in[2];
    const float* Wv = (const float*)d_in[3];
    const float* Wo = (const float*)d_in[4];
    float* out = (float*)d_out;

    const size_t per = (size_t)BATCH * NHEAD * SEQ * HD;   // 3,145,728 floats
    float* Q = (float*)d_ws;
    float* K = Q + per;
    float* V = K + per;
    float* O = V + per;       // total 4 * 12.6 MB = 50.3 MB of d_ws

    dim3 g1(BATCH * SEQ / 64, DM / 64, 3);   // 64 x 12 x 3
    qkv_gemm<<<g1, 256, 0, stream>>>(x, Wq, Wk, Wv, Q, K, V);

    dim3 g2(SEQ / 64, BATCH * NHEAD);        // 32 x 24
    attn_fwd<<<g2, 256, 0, stream>>>(Q, K, V, O);

    dim3 g3(BATCH * SEQ / 64, DM / 64);      // 64 x 12
    out_gemm<<<g3, 256, 0, stream>>>(O, Wo, out);
}

// Round 3
// 236.483 us; speedup vs baseline: 4.4004x; 4.4004x over previous
//
#include <hip/hip_runtime.h>
#include <math.h>

#define NHEAD 12
#define HD    64
#define SEQ   2048
#define BATCH 2
#define DM    768

typedef unsigned short u16;
typedef __attribute__((ext_vector_type(8))) short bf16x8;   // 8 bf16 = 4 VGPR
typedef __attribute__((ext_vector_type(8))) unsigned short u16x8;
typedef __attribute__((ext_vector_type(4))) float f32x4;

__device__ __forceinline__ u16 f2bf(float f) {
    unsigned u = __builtin_bit_cast(unsigned, f);
    return (u16)((u + 0x7fffu + ((u >> 16) & 1u)) >> 16);    // RNE
}
__device__ __forceinline__ bf16x8 as_bf16x8(uint4 v) { return __builtin_bit_cast(bf16x8, v); }
__device__ __forceinline__ u16x8  as_u16x8(uint4 v)  { return __builtin_bit_cast(u16x8, v); }
__device__ __forceinline__ f32x4 mfma16(bf16x8 a, bf16x8 b, f32x4 c) {
    return __builtin_amdgcn_mfma_f32_16x16x32_bf16(a, b, c, 0, 0, 0);
}

// ---------------------------------------------------------------------------
// fp32 -> bf16 conversion (vectorized), exact-size grids
// ---------------------------------------------------------------------------
__global__ void cvt4(const float* __restrict__ s, u16* __restrict__ d, int n4) {
    int i = blockIdx.x * blockDim.x + threadIdx.x;
    if (i < n4) {
        float4 v = ((const float4*)s)[i];
        ushort4 o;
        o.x = f2bf(v.x); o.y = f2bf(v.y); o.z = f2bf(v.z); o.w = f2bf(v.w);
        ((ushort4*)d)[i] = o;
    }
}

// ---------------------------------------------------------------------------
// QKV projection, bf16 MFMA.  C = X @ W^T, both operands k-contiguous rows.
// 128x128 tile, BK=32, 4 waves (2x2), 16x16x32 MFMA, 4x4 frags/wave.
// LDS rows padded to 40 u16 (80B) -> frag ds_read_b128 conflict-free.
// Epilogue writes bf16 directly in [B,H,S,hd].
// ---------------------------------------------------------------------------
__global__ __launch_bounds__(256)
void qkv_mfma(const u16* __restrict__ X,
              const u16* __restrict__ Wq, const u16* __restrict__ Wk,
              const u16* __restrict__ Wv,
              u16* __restrict__ Q, u16* __restrict__ K, u16* __restrict__ V)
{
    const u16* W = blockIdx.z == 0 ? Wq : blockIdx.z == 1 ? Wk : Wv;
    u16*       Y = blockIdx.z == 0 ? Q  : blockIdx.z == 1 ? K  : V;
    const int m0 = blockIdx.x * 128, n0 = blockIdx.y * 128;

    __shared__ __align__(16) u16 As[128 * 40];
    __shared__ __align__(16) u16 Bs[128 * 40];

    const int tid = threadIdx.x;
    const int w = tid >> 6, l = tid & 63, lg = l >> 4, lr = l & 15;
    const int wr = w >> 1, wc = w & 1;
    const int srow = tid >> 1, sh = tid & 1;            // staging row/half

    const u16* ga = X + (size_t)(m0 + srow) * DM + sh * 16;
    const u16* gb = W + (size_t)(n0 + srow) * DM + sh * 16;
    const int sidx = srow * 40 + sh * 16;

    f32x4 acc[4][4];
    #pragma unroll
    for (int i = 0; i < 4; ++i)
        #pragma unroll
        for (int j = 0; j < 4; ++j) acc[i][j] = (f32x4){0.f, 0.f, 0.f, 0.f};

    for (int k0 = 0; k0 < DM; k0 += 32) {
        uint4 a0 = *(const uint4*)(ga + k0);
        uint4 a1 = *(const uint4*)(ga + k0 + 8);
        uint4 b0 = *(const uint4*)(gb + k0);
        uint4 b1 = *(const uint4*)(gb + k0 + 8);
        __syncthreads();
        *(uint4*)&As[sidx] = a0; *(uint4*)&As[sidx + 8] = a1;
        *(uint4*)&Bs[sidx] = b0; *(uint4*)&Bs[sidx + 8] = b1;
        __syncthreads();
        bf16x8 af[4], bfr[4];
        #pragma unroll
        for (int i = 0; i < 4; ++i) {
            af[i]  = as_bf16x8(*(const uint4*)&As[(wr * 64 + i * 16 + lr) * 40 + lg * 8]);
            bfr[i] = as_bf16x8(*(const uint4*)&Bs[(wc * 64 + i * 16 + lr) * 40 + lg * 8]);
        }
        #pragma unroll
        for (int i = 0; i < 4; ++i)
            #pragma unroll
            for (int j = 0; j < 4; ++j)
                acc[i][j] = mfma16(af[i], bfr[j], acc[i][j]);
    }

    #pragma unroll
    for (int i = 0; i < 4; ++i) {
        const int mb = m0 + wr * 64 + i * 16 + lg * 4;
        #pragma unroll
        for (int j = 0; j < 4; ++j) {
            const int n = n0 + wc * 64 + j * 16 + lr;
            const int h = n >> 6, dc = n & 63;
            #pragma unroll
            for (int r = 0; r < 4; ++r) {
                const int m = mb + r;
                const int b = m >> 11, s2 = m & 2047;
                Y[(((size_t)b * NHEAD + h) * SEQ + s2) * HD + dc] = f2bf(acc[i][j][r]);
            }
        }
    }
}

// ---------------------------------------------------------------------------
// Flash attention, bf16 MFMA, fp32 softmax.
// Work-balanced pairing: block p handles 32-row q-subtiles p and 63-p ->
// exactly 33 compute-tiles per block.  2 waves; wave w owns 16 q-rows of
// each subtile.  K in XOR-swizzled LDS; V transposed (Vt[d][s]) at staging;
// P through per-wave LDS region (no cross-wave dependency).
// ---------------------------------------------------------------------------
__global__ __launch_bounds__(128)
void attn_mfma(const u16* __restrict__ Qg, const u16* __restrict__ Kg,
               const u16* __restrict__ Vg, u16* __restrict__ Og)
{
    const int p  = blockIdx.x;            // 0..31
    const int bh = blockIdx.y;            // 0..23
    const size_t base = (size_t)bh * SEQ * HD;
    const u16* Qb = Qg + base;
    const u16* Kb = Kg + base;
    const u16* Vb = Vg + base;
    u16*       Ob = Og + base;

    __shared__ __align__(16) u16 Ks[64 * 64];      // [s][d], swizzled
    __shared__ __align__(16) u16 Vt[64 * 64];      // [d][s], swizzled
    __shared__ __align__(16) u16 Ps[2 * 16 * 64];  // per-wave P, swizzled

    const int tid = threadIdx.x;
    const int w = tid >> 6, l = tid & 63, lg = l >> 4, lr = l & 15;

    const int qb0 = p * 32;               // lo subtile base
    const int qb1 = (63 - p) * 32;        // hi subtile base
    const int ke0 = (qb0 + 31) >> 6;      // last k-tile index (inclusive)
    const int ke1 = (qb1 + 31) >> 6;

    // Q fragments in registers: [sub][k-half]
    bf16x8 qf[2][2];
    #pragma unroll
    for (int sub = 0; sub < 2; ++sub) {
        const int qrow = (sub ? qb1 : qb0) + w * 16 + lr;
        #pragma unroll
        for (int kh = 0; kh < 2; ++kh)
            qf[sub][kh] = as_bf16x8(*(const uint4*)(Qb + (size_t)qrow * HD + kh * 32 + lg * 8));
    }

    float ms[2][4], ls[2][4];
    f32x4 ov[2][4];
    #pragma unroll
    for (int sub = 0; sub < 2; ++sub)
        #pragma unroll
        for (int r = 0; r < 4; ++r) {
            ms[sub][r] = -INFINITY; ls[sub][r] = 0.f;
            ov[sub][r] = (f32x4){0.f, 0.f, 0.f, 0.f};
        }

    const int srow = l;                   // staging: row 0..63
    const int hb   = w;                   // staging: which 32-element half

    for (int kt = 0; kt <= ke1; ++kt) {
        const int k0 = kt * 64;

        // issue global loads before the barrier (overlap with prev compute)
        const u16* kp = Kb + (size_t)(k0 + srow) * HD + hb * 32;
        const u16* vp = Vb + (size_t)(k0 + srow) * HD + hb * 32;
        uint4 kq[4], vq[4];
        #pragma unroll
        for (int q = 0; q < 4; ++q) kq[q] = *(const uint4*)(kp + q * 8);
        #pragma unroll
        for (int q = 0; q < 4; ++q) vq[q] = *(const uint4*)(vp + q * 8);

        __syncthreads();                  // prev tile's frag reads done
        #pragma unroll
        for (int q = 0; q < 4; ++q) {
            const int cb = hb * 64 + q * 16;
            *(uint4*)&Ks[srow * 64 + ((cb ^ ((srow & 7) << 4)) >> 1)] = kq[q];
        }
        #pragma unroll
        for (int q = 0; q < 4; ++q) {
            u16x8 vv = as_u16x8(vq[q]);
            #pragma unroll
            for (int e = 0; e < 8; ++e) {
                const int d = hb * 32 + q * 8 + e;
                Vt[d * 64 + (((srow * 2) ^ ((d & 7) << 4)) >> 1)] = vv[e];
            }
        }
        __syncthreads();                  // K/V tile visible

        #pragma unroll
        for (int sub = 0; sub < 2; ++sub) {
            const int qbase = sub ? qb1 : qb0;
            const int kend  = sub ? ke1 : ke0;
            if (kt > kend) continue;      // wave-uniform

            // --- QK^T ---
            f32x4 sc[4];
            #pragma unroll
            for (int nj = 0; nj < 4; ++nj) sc[nj] = (f32x4){0.f, 0.f, 0.f, 0.f};
            #pragma unroll
            for (int kh = 0; kh < 2; ++kh) {
                #pragma unroll
                for (int nj = 0; nj < 4; ++nj) {
                    const int s  = nj * 16 + lr;
                    const int cb = lg * 16 + kh * 64;
                    bf16x8 kf = as_bf16x8(*(const uint4*)&Ks[s * 64 + ((cb ^ ((s & 7) << 4)) >> 1)]);
                    sc[nj] = mfma16(qf[sub][kh], kf, sc[nj]);
                }
            }

            // --- scale + causal mask (only the last k-tile is partial) ---
            const bool lastt = (kt == kend);
            #pragma unroll
            for (int nj = 0; nj < 4; ++nj) {
                const int kk = k0 + nj * 16 + lr;
                #pragma unroll
                for (int r = 0; r < 4; ++r) {
                    float v = sc[nj][r] * 0.125f;
                    if (lastt) {
                        const int qrow = qbase + w * 16 + lg * 4 + r;
                        if (kk > qrow) v = -INFINITY;
                    }
                    sc[nj][r] = v;
                }
            }

            // --- online softmax (row r of each 16-lane group; 16-lane butterfly) ---
            float fac[4];
            #pragma unroll
            for (int r = 0; r < 4; ++r) {
                float rm = fmaxf(fmaxf(sc[0][r], sc[1][r]), fmaxf(sc[2][r], sc[3][r]));
                rm = fmaxf(rm, __shfl_xor(rm, 1));
                rm = fmaxf(rm, __shfl_xor(rm, 2));
                rm = fmaxf(rm, __shfl_xor(rm, 4));
                rm = fmaxf(rm, __shfl_xor(rm, 8));
                const float mo = ms[sub][r];
                const float mn = fmaxf(mo, rm);
                const float f  = __expf(mo - mn);
                ms[sub][r] = mn; fac[r] = f;
                float rs = 0.f;
                #pragma unroll
                for (int nj = 0; nj < 4; ++nj) {
                    const float pv = __expf(sc[nj][r] - mn);
                    sc[nj][r] = pv;
                    rs += pv;
                }
                rs += __shfl_xor(rs, 1); rs += __shfl_xor(rs, 2);
                rs += __shfl_xor(rs, 4); rs += __shfl_xor(rs, 8);
                ls[sub][r] = ls[sub][r] * f + rs;
            }

            // --- rescale O, publish P (per-wave region; no barrier needed) ---
            #pragma unroll
            for (int dj = 0; dj < 4; ++dj)
                #pragma unroll
                for (int r = 0; r < 4; ++r)
                    ov[sub][dj][r] *= fac[r];
            #pragma unroll
            for (int nj = 0; nj < 4; ++nj)
                #pragma unroll
                for (int r = 0; r < 4; ++r) {
                    const int row = lg * 4 + r, col = nj * 16 + lr;
                    Ps[w * 1024 + row * 64 + (((col * 2) ^ ((row & 7) << 4)) >> 1)] = f2bf(sc[nj][r]);
                }

            // --- PV ---
            #pragma unroll
            for (int ks = 0; ks < 2; ++ks) {
                const int cb = lg * 16 + ks * 64;
                bf16x8 pa = as_bf16x8(*(const uint4*)&Ps[w * 1024 + lr * 64 + ((cb ^ ((lr & 7) << 4)) >> 1)]);
                #pragma unroll
                for (int dj = 0; dj < 4; ++dj) {
                    const int d = dj * 16 + lr;
                    bf16x8 vf = as_bf16x8(*(const uint4*)&Vt[d * 64 + ((cb ^ ((d & 7) << 4)) >> 1)]);
                    ov[sub][dj] = mfma16(pa, vf, ov[sub][dj]);
                }
            }
        }
    }

    // --- epilogue: O /= l, write bf16 [B,H,S,hd] ---
    #pragma unroll
    for (int sub = 0; sub < 2; ++sub) {
        const int qbase = sub ? qb1 : qb0;
        #pragma unroll
        for (int r = 0; r < 4; ++r) {
            const float inv = 1.0f / ls[sub][r];
            const int row = qbase + w * 16 + lg * 4 + r;
            #pragma unroll
            for (int dj = 0; dj < 4; ++dj)
                Ob[(size_t)row * HD + dj * 16 + lr] = f2bf(ov[sub][dj][r] * inv);
        }
    }
}

// ---------------------------------------------------------------------------
// Output projection: out(f32) = O_gathered @ Wo^T.  Same GEMM structure;
// A-tile gathered from [B,H,S,hd] during staging.
// ---------------------------------------------------------------------------
__global__ __launch_bounds__(256)
void proj_mfma(const u16* __restrict__ O, const u16* __restrict__ Wo,
               float* __restrict__ out)
{
    const int m0 = blockIdx.x * 128, n0 = blockIdx.y * 128;

    __shared__ __align__(16) u16 As[128 * 40];
    __shared__ __align__(16) u16 Bs[128 * 40];

    const int tid = threadIdx.x;
    const int w = tid >> 6, l = tid & 63, lg = l >> 4, lr = l & 15;
    const int wr = w >> 1, wc = w & 1;
    const int srow = tid >> 1, sh = tid & 1;

    const int m = m0 + srow;
    const int b = m >> 11, s2 = m & 2047;
    const u16* gb = Wo + (size_t)(n0 + srow) * DM + sh * 16;
    const int sidx = srow * 40 + sh * 16;

    f32x4 acc[4][4];
    #pragma unroll
    for (int i = 0; i < 4; ++i)
        #pragma unroll
        for (int j = 0; j < 4; ++j) acc[i][j] = (f32x4){0.f, 0.f, 0.f, 0.f};

    for (int k0 = 0; k0 < DM; k0 += 32) {
        const int kk = k0 + sh * 16;                     // 16-aligned, single head
        const u16* ga = O + (((size_t)b * NHEAD + (kk >> 6)) * SEQ + s2) * HD + (kk & 63);
        uint4 a0 = *(const uint4*)(ga);
        uint4 a1 = *(const uint4*)(ga + 8);
        uint4 b0 = *(const uint4*)(gb + k0);
        uint4 b1 = *(const uint4*)(gb + k0 + 8);
        __syncthreads();
        *(uint4*)&As[sidx] = a0; *(uint4*)&As[sidx + 8] = a1;
        *(uint4*)&Bs[sidx] = b0; *(uint4*)&Bs[sidx + 8] = b1;
        __syncthreads();
        bf16x8 af[4], bfr[4];
        #pragma unroll
        for (int i = 0; i < 4; ++i) {
            af[i]  = as_bf16x8(*(const uint4*)&As[(wr * 64 + i * 16 + lr) * 40 + lg * 8]);
            bfr[i] = as_bf16x8(*(const uint4*)&Bs[(wc * 64 + i * 16 + lr) * 40 + lg * 8]);
        }
        #pragma unroll
        for (int i = 0; i < 4; ++i)
            #pragma unroll
            for (int j = 0; j < 4; ++j)
                acc[i][j] = mfma16(af[i], bfr[j], acc[i][j]);
    }

    #pragma unroll
    for (int i = 0; i < 4; ++i) {
        const int mb = m0 + wr * 64 + i * 16 + lg * 4;
        #pragma unroll
        for (int j = 0; j < 4; ++j) {
            const int n = n0 + wc * 64 + j * 16 + lr;
            #pragma unroll
            for (int r = 0; r < 4; ++r)
                out[(size_t)(mb + r) * DM + n] = acc[i][j][r];
        }
    }
}

// ---------------------------------------------------------------------------
extern "C" void kernel_launch(void* const* d_in, const int* in_sizes, int n_in,
                              void* d_out, int out_size, void* d_ws, size_t ws_size,
                              hipStream_t stream)
{
    const float* x  = (const float*)d_in[0];
    const float* Wq = (const float*)d_in[1];
    const float* Wk = (const float*)d_in[2];
    const float* Wv = (const float*)d_in[3];
    const float* Wo = (const float*)d_in[4];
    float* out = (float*)d_out;

    const size_t nx = (size_t)BATCH * SEQ * DM;     // 3,145,728
    const size_t nw = (size_t)DM * DM;              //   589,824
    const size_t nh = (size_t)BATCH * NHEAD * SEQ * HD;  // == nx

    u16* xb  = (u16*)d_ws;
    u16* wqb = xb  + nx;
    u16* wkb = wqb + nw;
    u16* wvb = wkb + nw;
    u16* wob = wvb + nw;
    u16* Qb  = wob + nw;
    u16* Kb  = Qb  + nh;
    u16* Vb  = Kb  + nh;
    u16* Ob  = Vb  + nh;     // total ~36 MB

    cvt4<<<(int)(nx / 4 / 256), 256, 0, stream>>>(x,  xb,  (int)(nx / 4));
    cvt4<<<(int)(nw / 4 / 256), 256, 0, stream>>>(Wq, wqb, (int)(nw / 4));
    cvt4<<<(int)(nw / 4 / 256), 256, 0, stream>>>(Wk, wkb, (int)(nw / 4));
    cvt4<<<(int)(nw / 4 / 256), 256, 0, stream>>>(Wv, wvb, (int)(nw / 4));
    cvt4<<<(int)(nw / 4 / 256), 256, 0, stream>>>(Wo, wob, (int)(nw / 4));

    dim3 g1(BATCH * SEQ / 128, DM / 128, 3);        // 32 x 6 x 3
    qkv_mfma<<<g1, 256, 0, stream>>>(xb, wqb, wkb, wvb, Qb, Kb, Vb);

    dim3 g2(32, BATCH * NHEAD);                     // 32 x 24, 128 threads
    attn_mfma<<<g2, 128, 0, stream>>>(Qb, Kb, Vb, Ob);

    dim3 g3(BATCH * SEQ / 128, DM / 128);           // 32 x 6
    proj_mfma<<<g3, 256, 0, stream>>>(Ob, wob, out);
}

// Round 7
// 216.504 us; speedup vs baseline: 4.8065x; 1.0923x over previous
//
#include <hip/hip_runtime.h>
#include <math.h>

#define NHEAD 12
#define HD    64
#define SEQ   2048
#define BATCH 2
#define DM    768

typedef unsigned short u16;
typedef __attribute__((ext_vector_type(8))) short bf16x8;   // 8 bf16 = 4 VGPR
typedef __attribute__((ext_vector_type(8))) unsigned short u16x8;
typedef __attribute__((ext_vector_type(4))) float f32x4;

__device__ __forceinline__ u16 f2bf(float f) {
    unsigned u = __builtin_bit_cast(unsigned, f);
    return (u16)((u + 0x7fffu + ((u >> 16) & 1u)) >> 16);    // RNE
}
__device__ __forceinline__ bf16x8 as_bf16x8(uint4 v) { return __builtin_bit_cast(bf16x8, v); }
__device__ __forceinline__ u16x8  as_u16x8(uint4 v)  { return __builtin_bit_cast(u16x8, v); }
__device__ __forceinline__ f32x4 mfma16(bf16x8 a, bf16x8 b, f32x4 c) {
    return __builtin_amdgcn_mfma_f32_16x16x32_bf16(a, b, c, 0, 0, 0);
}

// ---------------------------------------------------------------------------
// fp32 -> bf16 conversion
// ---------------------------------------------------------------------------
__global__ void cvt4(const float* __restrict__ s, u16* __restrict__ d, int n4) {
    int i = blockIdx.x * blockDim.x + threadIdx.x;
    if (i < n4) {
        float4 v = ((const float4*)s)[i];
        ushort4 o;
        o.x = f2bf(v.x); o.y = f2bf(v.y); o.z = f2bf(v.z); o.w = f2bf(v.w);
        ((ushort4*)d)[i] = o;
    }
}

// all 4 weight matrices in one launch (y selects)
__global__ void cvt4w(const float* __restrict__ s0, const float* __restrict__ s1,
                      const float* __restrict__ s2, const float* __restrict__ s3,
                      u16* __restrict__ d0, u16* __restrict__ d1,
                      u16* __restrict__ d2, u16* __restrict__ d3, int n4) {
    const float* s = blockIdx.y == 0 ? s0 : blockIdx.y == 1 ? s1 : blockIdx.y == 2 ? s2 : s3;
    u16*         d = blockIdx.y == 0 ? d0 : blockIdx.y == 1 ? d1 : blockIdx.y == 2 ? d2 : d3;
    int i = blockIdx.x * blockDim.x + threadIdx.x;
    if (i < n4) {
        float4 v = ((const float4*)s)[i];
        ushort4 o;
        o.x = f2bf(v.x); o.y = f2bf(v.y); o.z = f2bf(v.z); o.w = f2bf(v.w);
        ((ushort4*)d)[i] = o;
    }
}

// ---------------------------------------------------------------------------
// QKV projection, bf16 MFMA (verified R3)
// ---------------------------------------------------------------------------
__global__ __launch_bounds__(256)
void qkv_mfma(const u16* __restrict__ X,
              const u16* __restrict__ Wq, const u16* __restrict__ Wk,
              const u16* __restrict__ Wv,
              u16* __restrict__ Q, u16* __restrict__ K, u16* __restrict__ V)
{
    const u16* W = blockIdx.z == 0 ? Wq : blockIdx.z == 1 ? Wk : Wv;
    u16*       Y = blockIdx.z == 0 ? Q  : blockIdx.z == 1 ? K  : V;
    const int m0 = blockIdx.x * 128, n0 = blockIdx.y * 128;

    __shared__ __align__(16) u16 As[128 * 40];
    __shared__ __align__(16) u16 Bs[128 * 40];

    const int tid = threadIdx.x;
    const int w = tid >> 6, l = tid & 63, lg = l >> 4, lr = l & 15;
    const int wr = w >> 1, wc = w & 1;
    const int srow = tid >> 1, sh = tid & 1;

    const u16* ga = X + (size_t)(m0 + srow) * DM + sh * 16;
    const u16* gb = W + (size_t)(n0 + srow) * DM + sh * 16;
    const int sidx = srow * 40 + sh * 16;

    f32x4 acc[4][4];
    #pragma unroll
    for (int i = 0; i < 4; ++i)
        #pragma unroll
        for (int j = 0; j < 4; ++j) acc[i][j] = (f32x4){0.f, 0.f, 0.f, 0.f};

    for (int k0 = 0; k0 < DM; k0 += 32) {
        uint4 a0 = *(const uint4*)(ga + k0);
        uint4 a1 = *(const uint4*)(ga + k0 + 8);
        uint4 b0 = *(const uint4*)(gb + k0);
        uint4 b1 = *(const uint4*)(gb + k0 + 8);
        __syncthreads();
        *(uint4*)&As[sidx] = a0; *(uint4*)&As[sidx + 8] = a1;
        *(uint4*)&Bs[sidx] = b0; *(uint4*)&Bs[sidx + 8] = b1;
        __syncthreads();
        bf16x8 af[4], bfr[4];
        #pragma unroll
        for (int i = 0; i < 4; ++i) {
            af[i]  = as_bf16x8(*(const uint4*)&As[(wr * 64 + i * 16 + lr) * 40 + lg * 8]);
            bfr[i] = as_bf16x8(*(const uint4*)&Bs[(wc * 64 + i * 16 + lr) * 40 + lg * 8]);
        }
        __builtin_amdgcn_s_setprio(1);
        #pragma unroll
        for (int i = 0; i < 4; ++i)
            #pragma unroll
            for (int j = 0; j < 4; ++j)
                acc[i][j] = mfma16(af[i], bfr[j], acc[i][j]);
        __builtin_amdgcn_s_setprio(0);
    }

    #pragma unroll
    for (int i = 0; i < 4; ++i) {
        const int mb = m0 + wr * 64 + i * 16 + lg * 4;
        #pragma unroll
        for (int j = 0; j < 4; ++j) {
            const int n = n0 + wc * 64 + j * 16 + lr;
            const int h = n >> 6, dc = n & 63;
            #pragma unroll
            for (int r = 0; r < 4; ++r) {
                const int m = mb + r;
                const int b = m >> 11, s2 = m & 2047;
                Y[(((size_t)b * NHEAD + h) * SEQ + s2) * HD + dc] = f2bf(acc[i][j][r]);
            }
        }
    }
}

// ---------------------------------------------------------------------------
// Flash attention v2: 4 waves x 16 q-rows, contiguous 64-row block.
// All waves share kend = q0>>6 (zero divergence); longest blocks launch
// first (q0 = (31-bx)*64).  3072 waves total -> 3 waves/SIMD.
// K swizzle: byte-col ^ ((row&7)<<4)  (write+read, verified 0-conflict).
// Vt swizzle: byte-col ^ (CS(d)<<4), CS(d) = (d&7)^((d>>3)&7)  — needed
// because staging lanes now spread over d (4 d-groups would alias banks
// under the d&7-only swizzle).  Applied on BOTH write and read (rule #21).
// ---------------------------------------------------------------------------
__global__ __launch_bounds__(256)
void attn_mfma(const u16* __restrict__ Qg, const u16* __restrict__ Kg,
               const u16* __restrict__ Vg, u16* __restrict__ Og)
{
    const int q0 = (31 - blockIdx.x) * 64;     // longest-first
    const int bh = blockIdx.y;                 // 0..23
    const int kend = q0 >> 6;
    const size_t base = (size_t)bh * SEQ * HD;
    const u16* Qb = Qg + base;
    const u16* Kb = Kg + base;
    const u16* Vb = Vg + base;
    u16*       Ob = Og + base;

    __shared__ __align__(16) u16 Ks[64 * 64];      // [key][d], swizzled by key&7
    __shared__ __align__(16) u16 Vt[64 * 64];      // [d][key], swizzled by CS(d)
    __shared__ __align__(16) u16 Ps[4 * 16 * 64];  // per-wave P, swizzled by row&7

    const int tid = threadIdx.x;
    const int w = tid >> 6, l = tid & 63, lg = l >> 4, lr = l & 15;

    // staging map: 4 threads per 64-u16 row
    const int srow = w * 16 + (l >> 2);        // 0..63
    const int c0   = (l & 3) * 16;             // u16 col base; covers c0..c0+15

    // Q fragments (wave's 16 rows)
    const int qrow = q0 + w * 16 + lr;
    bf16x8 qf[2];
    #pragma unroll
    for (int kh = 0; kh < 2; ++kh)
        qf[kh] = as_bf16x8(*(const uint4*)(Qb + (size_t)qrow * HD + kh * 32 + lg * 8));

    float ms[4], ls[4];
    f32x4 ov[4];
    #pragma unroll
    for (int r = 0; r < 4; ++r) { ms[r] = -INFINITY; ls[r] = 0.f; }
    #pragma unroll
    for (int dj = 0; dj < 4; ++dj) ov[dj] = (f32x4){0.f, 0.f, 0.f, 0.f};

    for (int kt = 0; kt <= kend; ++kt) {
        const int k0 = kt * 64;

        // issue global loads early (overlap with prev tile's compute)
        const u16* kp = Kb + (size_t)(k0 + srow) * HD + c0;
        const u16* vp = Vb + (size_t)(k0 + srow) * HD + c0;
        uint4 kq0 = *(const uint4*)(kp);
        uint4 kq1 = *(const uint4*)(kp + 8);
        uint4 vq0 = *(const uint4*)(vp);
        uint4 vq1 = *(const uint4*)(vp + 8);

        __syncthreads();                  // prev tile's frag reads done
        {   // K: two b128 writes, swizzled by srow&7
            const int sw = (srow & 7) << 4;
            *(uint4*)&Ks[srow * 64 + (((c0 * 2) ^ sw) >> 1)]        = kq0;
            *(uint4*)&Ks[srow * 64 + ((((c0 + 8) * 2) ^ sw) >> 1)]  = kq1;
        }
        #pragma unroll
        for (int h = 0; h < 2; ++h) {     // V transpose: 16 scalar writes, CS swizzle
            u16x8 vv = as_u16x8(h ? vq1 : vq0);
            #pragma unroll
            for (int e = 0; e < 8; ++e) {
                const int d  = c0 + h * 8 + e;
                const int cs = (d & 7) ^ ((d >> 3) & 7);
                Vt[d * 64 + (((srow * 2) ^ (cs << 4)) >> 1)] = vv[e];
            }
        }
        __syncthreads();                  // K/V tile visible

        // --- QK^T ---
        f32x4 sc[4];
        #pragma unroll
        for (int nj = 0; nj < 4; ++nj) sc[nj] = (f32x4){0.f, 0.f, 0.f, 0.f};
        __builtin_amdgcn_s_setprio(1);
        #pragma unroll
        for (int kh = 0; kh < 2; ++kh) {
            #pragma unroll
            for (int nj = 0; nj < 4; ++nj) {
                const int s  = nj * 16 + lr;
                const int cb = kh * 64 + lg * 16;   // byte col
                bf16x8 kf = as_bf16x8(*(const uint4*)&Ks[s * 64 + ((cb ^ ((s & 7) << 4)) >> 1)]);
                sc[nj] = mfma16(qf[kh], kf, sc[nj]);
            }
        }
        __builtin_amdgcn_s_setprio(0);

        // --- scale + causal mask (only last k-tile is partial) ---
        const bool lastt = (kt == kend);
        #pragma unroll
        for (int nj = 0; nj < 4; ++nj) {
            const int kk = k0 + nj * 16 + lr;
            #pragma unroll
            for (int r = 0; r < 4; ++r) {
                float v = sc[nj][r] * 0.125f;
                if (lastt && kk > (q0 + w * 16 + lg * 4 + r)) v = -INFINITY;
                sc[nj][r] = v;
            }
        }

        // --- online softmax (4 rows, 16-lane butterflies) ---
        float fac[4];
        #pragma unroll
        for (int r = 0; r < 4; ++r) {
            float rm = fmaxf(fmaxf(sc[0][r], sc[1][r]), fmaxf(sc[2][r], sc[3][r]));
            rm = fmaxf(rm, __shfl_xor(rm, 1));
            rm = fmaxf(rm, __shfl_xor(rm, 2));
            rm = fmaxf(rm, __shfl_xor(rm, 4));
            rm = fmaxf(rm, __shfl_xor(rm, 8));
            const float mo = ms[r];
            const float mn = fmaxf(mo, rm);
            const float f  = __expf(mo - mn);
            ms[r] = mn; fac[r] = f;
            float rs = 0.f;
            #pragma unroll
            for (int nj = 0; nj < 4; ++nj) {
                const float pv = __expf(sc[nj][r] - mn);
                sc[nj][r] = pv;
                rs += pv;
            }
            rs += __shfl_xor(rs, 1); rs += __shfl_xor(rs, 2);
            rs += __shfl_xor(rs, 4); rs += __shfl_xor(rs, 8);
            ls[r] = ls[r] * f + rs;
        }

        // --- rescale O, publish P (wave-private region, no barrier) ---
        #pragma unroll
        for (int dj = 0; dj < 4; ++dj)
            #pragma unroll
            for (int r = 0; r < 4; ++r)
                ov[dj][r] *= fac[r];
        #pragma unroll
        for (int nj = 0; nj < 4; ++nj)
            #pragma unroll
            for (int r = 0; r < 4; ++r) {
                const int row = lg * 4 + r, col = nj * 16 + lr;
                Ps[w * 1024 + row * 64 + (((col * 2) ^ ((row & 7) << 4)) >> 1)] = f2bf(sc[nj][r]);
            }

        // --- PV ---
        __builtin_amdgcn_s_setprio(1);
        #pragma unroll
        for (int ks = 0; ks < 2; ++ks) {
            const int cb = ks * 64 + lg * 16;       // byte col (key offset)
            bf16x8 pa = as_bf16x8(*(const uint4*)&Ps[w * 1024 + lr * 64 + ((cb ^ ((lr & 7) << 4)) >> 1)]);
            #pragma unroll
            for (int dj = 0; dj < 4; ++dj) {
                const int d  = dj * 16 + lr;
                const int cs = (d & 7) ^ ((d >> 3) & 7);
                bf16x8 vf = as_bf16x8(*(const uint4*)&Vt[d * 64 + ((cb ^ (cs << 4)) >> 1)]);
                ov[dj] = mfma16(pa, vf, ov[dj]);
            }
        }
        __builtin_amdgcn_s_setprio(0);
    }

    // --- epilogue ---
    #pragma unroll
    for (int r = 0; r < 4; ++r) {
        const float inv = 1.0f / ls[r];
        const int row = q0 + w * 16 + lg * 4 + r;
        #pragma unroll
        for (int dj = 0; dj < 4; ++dj)
            Ob[(size_t)row * HD + dj * 16 + lr] = f2bf(ov[dj][r] * inv);
    }
}

// ---------------------------------------------------------------------------
// Output projection (verified R3)
// ---------------------------------------------------------------------------
__global__ __launch_bounds__(256)
void proj_mfma(const u16* __restrict__ O, const u16* __restrict__ Wo,
               float* __restrict__ out)
{
    const int m0 = blockIdx.x * 128, n0 = blockIdx.y * 128;

    __shared__ __align__(16) u16 As[128 * 40];
    __shared__ __align__(16) u16 Bs[128 * 40];

    const int tid = threadIdx.x;
    const int w = tid >> 6, l = tid & 63, lg = l >> 4, lr = l & 15;
    const int wr = w >> 1, wc = w & 1;
    const int srow = tid >> 1, sh = tid & 1;

    const int m = m0 + srow;
    const int b = m >> 11, s2 = m & 2047;
    const u16* gb = Wo + (size_t)(n0 + srow) * DM + sh * 16;
    const int sidx = srow * 40 + sh * 16;

    f32x4 acc[4][4];
    #pragma unroll
    for (int i = 0; i < 4; ++i)
        #pragma unroll
        for (int j = 0; j < 4; ++j) acc[i][j] = (f32x4){0.f, 0.f, 0.f, 0.f};

    for (int k0 = 0; k0 < DM; k0 += 32) {
        const int kk = k0 + sh * 16;
        const u16* ga = O + (((size_t)b * NHEAD + (kk >> 6)) * SEQ + s2) * HD + (kk & 63);
        uint4 a0 = *(const uint4*)(ga);
        uint4 a1 = *(const uint4*)(ga + 8);
        uint4 b0 = *(const uint4*)(gb + k0);
        uint4 b1 = *(const uint4*)(gb + k0 + 8);
        __syncthreads();
        *(uint4*)&As[sidx] = a0; *(uint4*)&As[sidx + 8] = a1;
        *(uint4*)&Bs[sidx] = b0; *(uint4*)&Bs[sidx + 8] = b1;
        __syncthreads();
        bf16x8 af[4], bfr[4];
        #pragma unroll
        for (int i = 0; i < 4; ++i) {
            af[i]  = as_bf16x8(*(const uint4*)&As[(wr * 64 + i * 16 + lr) * 40 + lg * 8]);
            bfr[i] = as_bf16x8(*(const uint4*)&Bs[(wc * 64 + i * 16 + lr) * 40 + lg * 8]);
        }
        __builtin_amdgcn_s_setprio(1);
        #pragma unroll
        for (int i = 0; i < 4; ++i)
            #pragma unroll
            for (int j = 0; j < 4; ++j)
                acc[i][j] = mfma16(af[i], bfr[j], acc[i][j]);
        __builtin_amdgcn_s_setprio(0);
    }

    #pragma unroll
    for (int i = 0; i < 4; ++i) {
        const int mb = m0 + wr * 64 + i * 16 + lg * 4;
        #pragma unroll
        for (int j = 0; j < 4; ++j) {
            const int n = n0 + wc * 64 + j * 16 + lr;
            #pragma unroll
            for (int r = 0; r < 4; ++r)
                out[(size_t)(mb + r) * DM + n] = acc[i][j][r];
        }
    }
}

// ---------------------------------------------------------------------------
extern "C" void kernel_launch(void* const* d_in, const int* in_sizes, int n_in,
                              void* d_out, int out_size, void* d_ws, size_t ws_size,
                              hipStream_t stream)
{
    const float* x  = (const float*)d_in[0];
    const float* Wq = (const float*)d_in[1];
    const float* Wk = (const float*)d_in[2];
    const float* Wv = (const float*)d_in[3];
    const float* Wo = (const float*)d_in[4];
    float* out = (float*)d_out;

    const size_t nx = (size_t)BATCH * SEQ * DM;          // 3,145,728
    const size_t nw = (size_t)DM * DM;                   //   589,824
    const size_t nh = (size_t)BATCH * NHEAD * SEQ * HD;  // == nx

    u16* xb  = (u16*)d_ws;
    u16* wqb = xb  + nx;
    u16* wkb = wqb + nw;
    u16* wvb = wkb + nw;
    u16* wob = wvb + nw;
    u16* Qb  = wob + nw;
    u16* Kb  = Qb  + nh;
    u16* Vb  = Kb  + nh;
    u16* Ob  = Vb  + nh;

    cvt4<<<(int)(nx / 4 / 256), 256, 0, stream>>>(x, xb, (int)(nx / 4));
    dim3 gw((unsigned)(nw / 4 / 256), 4);
    cvt4w<<<gw, 256, 0, stream>>>(Wq, Wk, Wv, Wo, wqb, wkb, wvb, wob, (int)(nw / 4));

    dim3 g1(BATCH * SEQ / 128, DM / 128, 3);        // 32 x 6 x 3
    qkv_mfma<<<g1, 256, 0, stream>>>(xb, wqb, wkb, wvb, Qb, Kb, Vb);

    dim3 g2(32, BATCH * NHEAD);                     // 32 x 24, 256 threads
    attn_mfma<<<g2, 256, 0, stream>>>(Qb, Kb, Vb, Ob);

    dim3 g3(BATCH * SEQ / 128, DM / 128);           // 32 x 6
    proj_mfma<<<g3, 256, 0, stream>>>(Ob, wob, out);
}

// Round 8
// 209.497 us; speedup vs baseline: 4.9672x; 1.0335x over previous
//
#include <hip/hip_runtime.h>
#include <math.h>

#define NHEAD 12
#define HD    64
#define SEQ   2048
#define BATCH 2
#define DM    768

typedef unsigned short u16;
typedef __attribute__((ext_vector_type(8))) short bf16x8;   // 8 bf16 = 4 VGPR
typedef __attribute__((ext_vector_type(8))) unsigned short u16x8;
typedef __attribute__((ext_vector_type(4))) float f32x4;

__device__ __forceinline__ u16 f2bf(float f) {
    unsigned u = __builtin_bit_cast(unsigned, f);
    return (u16)((u + 0x7fffu + ((u >> 16) & 1u)) >> 16);    // RNE
}
__device__ __forceinline__ bf16x8 as_bf16x8(uint4 v) { return __builtin_bit_cast(bf16x8, v); }
__device__ __forceinline__ u16x8  as_u16x8(uint4 v)  { return __builtin_bit_cast(u16x8, v); }
__device__ __forceinline__ f32x4 mfma16(bf16x8 a, bf16x8 b, f32x4 c) {
    return __builtin_amdgcn_mfma_f32_16x16x32_bf16(a, b, c, 0, 0, 0);
}

// ---------------------------------------------------------------------------
// fp32 -> bf16 conversion
// ---------------------------------------------------------------------------
__global__ void cvt4(const float* __restrict__ s, u16* __restrict__ d, int n4) {
    int i = blockIdx.x * blockDim.x + threadIdx.x;
    if (i < n4) {
        float4 v = ((const float4*)s)[i];
        ushort4 o;
        o.x = f2bf(v.x); o.y = f2bf(v.y); o.z = f2bf(v.z); o.w = f2bf(v.w);
        ((ushort4*)d)[i] = o;
    }
}

__global__ void cvt4w(const float* __restrict__ s0, const float* __restrict__ s1,
                      const float* __restrict__ s2, const float* __restrict__ s3,
                      u16* __restrict__ d0, u16* __restrict__ d1,
                      u16* __restrict__ d2, u16* __restrict__ d3, int n4) {
    const float* s = blockIdx.y == 0 ? s0 : blockIdx.y == 1 ? s1 : blockIdx.y == 2 ? s2 : s3;
    u16*         d = blockIdx.y == 0 ? d0 : blockIdx.y == 1 ? d1 : blockIdx.y == 2 ? d2 : d3;
    int i = blockIdx.x * blockDim.x + threadIdx.x;
    if (i < n4) {
        float4 v = ((const float4*)s)[i];
        ushort4 o;
        o.x = f2bf(v.x); o.y = f2bf(v.y); o.z = f2bf(v.z); o.w = f2bf(v.w);
        ((ushort4*)d)[i] = o;
    }
}

// ---------------------------------------------------------------------------
// QKV projection, bf16 MFMA (verified R3).  NEW: Q output pre-scaled by
// 1/sqrt(hd)=0.125 so attention needs no per-score scaling.
// ---------------------------------------------------------------------------
__global__ __launch_bounds__(256)
void qkv_mfma(const u16* __restrict__ X,
              const u16* __restrict__ Wq, const u16* __restrict__ Wk,
              const u16* __restrict__ Wv,
              u16* __restrict__ Q, u16* __restrict__ K, u16* __restrict__ V)
{
    const u16* W = blockIdx.z == 0 ? Wq : blockIdx.z == 1 ? Wk : Wv;
    u16*       Y = blockIdx.z == 0 ? Q  : blockIdx.z == 1 ? K  : V;
    const float osc = (blockIdx.z == 0) ? 0.125f : 1.0f;
    const int m0 = blockIdx.x * 128, n0 = blockIdx.y * 128;

    __shared__ __align__(16) u16 As[128 * 40];
    __shared__ __align__(16) u16 Bs[128 * 40];

    const int tid = threadIdx.x;
    const int w = tid >> 6, l = tid & 63, lg = l >> 4, lr = l & 15;
    const int wr = w >> 1, wc = w & 1;
    const int srow = tid >> 1, sh = tid & 1;

    const u16* ga = X + (size_t)(m0 + srow) * DM + sh * 16;
    const u16* gb = W + (size_t)(n0 + srow) * DM + sh * 16;
    const int sidx = srow * 40 + sh * 16;

    f32x4 acc[4][4];
    #pragma unroll
    for (int i = 0; i < 4; ++i)
        #pragma unroll
        for (int j = 0; j < 4; ++j) acc[i][j] = (f32x4){0.f, 0.f, 0.f, 0.f};

    for (int k0 = 0; k0 < DM; k0 += 32) {
        uint4 a0 = *(const uint4*)(ga + k0);
        uint4 a1 = *(const uint4*)(ga + k0 + 8);
        uint4 b0 = *(const uint4*)(gb + k0);
        uint4 b1 = *(const uint4*)(gb + k0 + 8);
        __syncthreads();
        *(uint4*)&As[sidx] = a0; *(uint4*)&As[sidx + 8] = a1;
        *(uint4*)&Bs[sidx] = b0; *(uint4*)&Bs[sidx + 8] = b1;
        __syncthreads();
        bf16x8 af[4], bfr[4];
        #pragma unroll
        for (int i = 0; i < 4; ++i) {
            af[i]  = as_bf16x8(*(const uint4*)&As[(wr * 64 + i * 16 + lr) * 40 + lg * 8]);
            bfr[i] = as_bf16x8(*(const uint4*)&Bs[(wc * 64 + i * 16 + lr) * 40 + lg * 8]);
        }
        __builtin_amdgcn_s_setprio(1);
        #pragma unroll
        for (int i = 0; i < 4; ++i)
            #pragma unroll
            for (int j = 0; j < 4; ++j)
                acc[i][j] = mfma16(af[i], bfr[j], acc[i][j]);
        __builtin_amdgcn_s_setprio(0);
    }

    #pragma unroll
    for (int i = 0; i < 4; ++i) {
        const int mb = m0 + wr * 64 + i * 16 + lg * 4;
        #pragma unroll
        for (int j = 0; j < 4; ++j) {
            const int n = n0 + wc * 64 + j * 16 + lr;
            const int h = n >> 6, dc = n & 63;
            #pragma unroll
            for (int r = 0; r < 4; ++r) {
                const int m = mb + r;
                const int b = m >> 11, s2 = m & 2047;
                Y[(((size_t)b * NHEAD + h) * SEQ + s2) * HD + dc] = f2bf(acc[i][j][r] * osc);
            }
        }
    }
}

// ---------------------------------------------------------------------------
// Flash attention v3: swapped QK^T (T12-adapted) + lane-local P (kappa
// permutation) + defer-max (T13).
//   sc[nj] = mfma(K, Q): lane (lg,lr) holds P[q-row=lr][key = nj*16+lg*4+r]
//   -> softmax reduce = 16 local ops + shfl_xor(16,32) [was 32 shuffles]
//   PV key order kappa(ks,lg,j) = (2ks+(j>>2))*16 + lg*4 + (j&3): A-frag is
//   LANE-LOCAL (8 cvt_pk, no LDS P); V-frag = 2x b64 reads from Vt under
//   the same kappa.  O-row state (row=lg*4+r) gets fac/l via ds_bpermute
//   (rescale tiles + epilogue only; defer-max skips rescale almost always).
// Q pre-scaled in qkv.  Grid/staging/swizzles unchanged from R7.
// ---------------------------------------------------------------------------
__global__ __launch_bounds__(256)
void attn_mfma(const u16* __restrict__ Qg, const u16* __restrict__ Kg,
               const u16* __restrict__ Vg, u16* __restrict__ Og)
{
    const int q0 = (31 - blockIdx.x) * 64;     // longest-first
    const int bh = blockIdx.y;                 // 0..23
    const int kend = q0 >> 6;
    const size_t base = (size_t)bh * SEQ * HD;
    const u16* Qb = Qg + base;
    const u16* Kb = Kg + base;
    const u16* Vb = Vg + base;
    u16*       Ob = Og + base;

    __shared__ __align__(16) u16 Ks[64 * 64];      // [key][d], swizzled by key&7
    __shared__ __align__(16) u16 Vt[64 * 64];      // [d][key], swizzled by CS(d)

    const int tid = threadIdx.x;
    const int w = tid >> 6, l = tid & 63, lg = l >> 4, lr = l & 15;

    // staging map: 4 threads per 64-u16 row
    const int srow = w * 16 + (l >> 2);        // 0..63
    const int c0   = (l & 3) * 16;             // u16 col base

    // Q fragments (wave's 16 rows); Q pre-scaled by 0.125 in qkv
    const int qrow = q0 + w * 16 + lr;
    bf16x8 qf[2];
    #pragma unroll
    for (int kh = 0; kh < 2; ++kh)
        qf[kh] = as_bf16x8(*(const uint4*)(Qb + (size_t)qrow * HD + kh * 32 + lg * 8));

    float ms = -INFINITY, lsum = 0.f;          // per-lane: state of q-row lr
    f32x4 ov[4];                               // O[row=lg*4+r][d=dj*16+lr]
    #pragma unroll
    for (int dj = 0; dj < 4; ++dj) ov[dj] = (f32x4){0.f, 0.f, 0.f, 0.f};

    for (int kt = 0; kt <= kend; ++kt) {
        const int k0 = kt * 64;

        // issue global loads early (overlap with prev tile's compute)
        const u16* kp = Kb + (size_t)(k0 + srow) * HD + c0;
        const u16* vp = Vb + (size_t)(k0 + srow) * HD + c0;
        uint4 kq0 = *(const uint4*)(kp);
        uint4 kq1 = *(const uint4*)(kp + 8);
        uint4 vq0 = *(const uint4*)(vp);
        uint4 vq1 = *(const uint4*)(vp + 8);

        __syncthreads();                  // prev tile's frag reads done
        {   // K: two b128 writes, swizzled by srow&7
            const int sw = (srow & 7) << 4;
            *(uint4*)&Ks[srow * 64 + (((c0 * 2) ^ sw) >> 1)]        = kq0;
            *(uint4*)&Ks[srow * 64 + ((((c0 + 8) * 2) ^ sw) >> 1)]  = kq1;
        }
        #pragma unroll
        for (int h = 0; h < 2; ++h) {     // V transpose: 16 scalar writes, CS swizzle
            u16x8 vv = as_u16x8(h ? vq1 : vq0);
            #pragma unroll
            for (int e = 0; e < 8; ++e) {
                const int d  = c0 + h * 8 + e;
                const int cs = (d & 7) ^ ((d >> 3) & 7);
                Vt[d * 64 + (((srow * 2) ^ (cs << 4)) >> 1)] = vv[e];
            }
        }
        __syncthreads();                  // K/V tile visible

        // --- QK^T, SWAPPED: sc[nj] = K_frag * Q_frag ---
        // D: col=lr=q-row, row=lg*4+r=key pos within nj block
        f32x4 sc[4];
        #pragma unroll
        for (int nj = 0; nj < 4; ++nj) sc[nj] = (f32x4){0.f, 0.f, 0.f, 0.f};
        __builtin_amdgcn_s_setprio(1);
        #pragma unroll
        for (int kh = 0; kh < 2; ++kh) {
            #pragma unroll
            for (int nj = 0; nj < 4; ++nj) {
                const int s  = nj * 16 + lr;
                const int cb = kh * 64 + lg * 16;   // byte col
                bf16x8 kf = as_bf16x8(*(const uint4*)&Ks[s * 64 + ((cb ^ ((s & 7) << 4)) >> 1)]);
                sc[nj] = mfma16(kf, qf[kh], sc[nj]);
            }
        }
        __builtin_amdgcn_s_setprio(0);

        // --- causal mask: only diagonal tile, wave-uniform branch ---
        if (kt == kend) {
            #pragma unroll
            for (int nj = 0; nj < 4; ++nj)
                #pragma unroll
                for (int r = 0; r < 4; ++r) {
                    const int key = k0 + nj * 16 + lg * 4 + r;
                    if (key > qrow) sc[nj][r] = -INFINITY;
                }
        }

        // --- online softmax, row = lr, data spread over 4 lg-groups ---
        float pm = sc[0][0];
        #pragma unroll
        for (int nj = 0; nj < 4; ++nj)
            #pragma unroll
            for (int r = 0; r < 4; ++r) pm = fmaxf(pm, sc[nj][r]);
        pm = fmaxf(pm, __shfl_xor(pm, 16));
        pm = fmaxf(pm, __shfl_xor(pm, 32));

        if (!__all(pm <= ms + 8.f)) {     // T13 defer-max: rescale rarely
            const float mn  = fmaxf(ms, pm);
            const float fac = __expf(ms - mn);
            ms = mn;
            lsum *= fac;
            const int fi = __builtin_bit_cast(int, fac);
            #pragma unroll
            for (int r = 0; r < 4; ++r) {  // fac for O-row lg*4+r lives in lane (lg*4+r)
                const float fr = __builtin_bit_cast(float,
                    __builtin_amdgcn_ds_bpermute((lg * 4 + r) * 4, fi));
                #pragma unroll
                for (int dj = 0; dj < 4; ++dj) ov[dj][r] *= fr;
            }
        }

        float rs = 0.f;
        #pragma unroll
        for (int nj = 0; nj < 4; ++nj)
            #pragma unroll
            for (int r = 0; r < 4; ++r) {
                const float p = __expf(sc[nj][r] - ms);
                sc[nj][r] = p;
                rs += p;
            }
        rs += __shfl_xor(rs, 16);
        rs += __shfl_xor(rs, 32);
        lsum += rs;

        // --- pack P (lane-local under kappa): 8 cvt_pk ---
        unsigned pw[4][2];
        #pragma unroll
        for (int nj = 0; nj < 4; ++nj) {
            asm("v_cvt_pk_bf16_f32 %0, %1, %2" : "=v"(pw[nj][0]) : "v"(sc[nj][0]), "v"(sc[nj][1]));
            asm("v_cvt_pk_bf16_f32 %0, %1, %2" : "=v"(pw[nj][1]) : "v"(sc[nj][2]), "v"(sc[nj][3]));
        }

        // --- PV: A = P (in-register), B = V under kappa (2x b64 per frag) ---
        __builtin_amdgcn_s_setprio(1);
        #pragma unroll
        for (int ks = 0; ks < 2; ++ks) {
            uint4 pa4;
            pa4.x = pw[2 * ks][0]; pa4.y = pw[2 * ks][1];
            pa4.z = pw[2 * ks + 1][0]; pa4.w = pw[2 * ks + 1][1];
            const bf16x8 pa = as_bf16x8(pa4);
            const int b0 = 64 * ks + 8 * lg;          // byte col of key0*2
            #pragma unroll
            for (int dj = 0; dj < 4; ++dj) {
                const int d  = dj * 16 + lr;
                const int cs = (d & 7) ^ ((d >> 3) & 7);
                const uint2 v0 = *(const uint2*)&Vt[d * 64 + ((b0 ^ (cs << 4)) >> 1)];
                const uint2 v1 = *(const uint2*)&Vt[d * 64 + (((b0 + 32) ^ (cs << 4)) >> 1)];
                uint4 vv; vv.x = v0.x; vv.y = v0.y; vv.z = v1.x; vv.w = v1.y;
                ov[dj] = mfma16(pa, as_bf16x8(vv), ov[dj]);
            }
        }
        __builtin_amdgcn_s_setprio(0);
    }

    // --- epilogue: l for O-row lg*4+r via bpermute ---
    const int li = __builtin_bit_cast(int, lsum);
    #pragma unroll
    for (int r = 0; r < 4; ++r) {
        const float lrow = __builtin_bit_cast(float,
            __builtin_amdgcn_ds_bpermute((lg * 4 + r) * 4, li));
        const float inv = 1.0f / lrow;
        const int row = q0 + w * 16 + lg * 4 + r;
        #pragma unroll
        for (int dj = 0; dj < 4; ++dj)
            Ob[(size_t)row * HD + dj * 16 + lr] = f2bf(ov[dj][r] * inv);
    }
}

// ---------------------------------------------------------------------------
// Output projection (verified R3)
// ---------------------------------------------------------------------------
__global__ __launch_bounds__(256)
void proj_mfma(const u16* __restrict__ O, const u16* __restrict__ Wo,
               float* __restrict__ out)
{
    const int m0 = blockIdx.x * 128, n0 = blockIdx.y * 128;

    __shared__ __align__(16) u16 As[128 * 40];
    __shared__ __align__(16) u16 Bs[128 * 40];

    const int tid = threadIdx.x;
    const int w = tid >> 6, l = tid & 63, lg = l >> 4, lr = l & 15;
    const int wr = w >> 1, wc = w & 1;
    const int srow = tid >> 1, sh = tid & 1;

    const int m = m0 + srow;
    const int b = m >> 11, s2 = m & 2047;
    const u16* gb = Wo + (size_t)(n0 + srow) * DM + sh * 16;
    const int sidx = srow * 40 + sh * 16;

    f32x4 acc[4][4];
    #pragma unroll
    for (int i = 0; i < 4; ++i)
        #pragma unroll
        for (int j = 0; j < 4; ++j) acc[i][j] = (f32x4){0.f, 0.f, 0.f, 0.f};

    for (int k0 = 0; k0 < DM; k0 += 32) {
        const int kk = k0 + sh * 16;
        const u16* ga = O + (((size_t)b * NHEAD + (kk >> 6)) * SEQ + s2) * HD + (kk & 63);
        uint4 a0 = *(const uint4*)(ga);
        uint4 a1 = *(const uint4*)(ga + 8);
        uint4 b0 = *(const uint4*)(gb + k0);
        uint4 b1 = *(const uint4*)(gb + k0 + 8);
        __syncthreads();
        *(uint4*)&As[sidx] = a0; *(uint4*)&As[sidx + 8] = a1;
        *(uint4*)&Bs[sidx] = b0; *(uint4*)&Bs[sidx + 8] = b1;
        __syncthreads();
        bf16x8 af[4], bfr[4];
        #pragma unroll
        for (int i = 0; i < 4; ++i) {
            af[i]  = as_bf16x8(*(const uint4*)&As[(wr * 64 + i * 16 + lr) * 40 + lg * 8]);
            bfr[i] = as_bf16x8(*(const uint4*)&Bs[(wc * 64 + i * 16 + lr) * 40 + lg * 8]);
        }
        __builtin_amdgcn_s_setprio(1);
        #pragma unroll
        for (int i = 0; i < 4; ++i)
            #pragma unroll
            for (int j = 0; j < 4; ++j)
                acc[i][j] = mfma16(af[i], bfr[j], acc[i][j]);
        __builtin_amdgcn_s_setprio(0);
    }

    #pragma unroll
    for (int i = 0; i < 4; ++i) {
        const int mb = m0 + wr * 64 + i * 16 + lg * 4;
        #pragma unroll
        for (int j = 0; j < 4; ++j) {
            const int n = n0 + wc * 64 + j * 16 + lr;
            #pragma unroll
            for (int r = 0; r < 4; ++r)
                out[(size_t)(mb + r) * DM + n] = acc[i][j][r];
        }
    }
}

// ---------------------------------------------------------------------------
extern "C" void kernel_launch(void* const* d_in, const int* in_sizes, int n_in,
                              void* d_out, int out_size, void* d_ws, size_t ws_size,
                              hipStream_t stream)
{
    const float* x  = (const float*)d_in[0];
    const float* Wq = (const float*)d_in[1];
    const float* Wk = (const float*)d_in[2];
    const float* Wv = (const float*)d_in[3];
    const float* Wo = (const float*)d_in[4];
    float* out = (float*)d_out;

    const size_t nx = (size_t)BATCH * SEQ * DM;          // 3,145,728
    const size_t nw = (size_t)DM * DM;                   //   589,824
    const size_t nh = (size_t)BATCH * NHEAD * SEQ * HD;  // == nx

    u16* xb  = (u16*)d_ws;
    u16* wqb = xb  + nx;
    u16* wkb = wqb + nw;
    u16* wvb = wkb + nw;
    u16* wob = wvb + nw;
    u16* Qb  = wob + nw;
    u16* Kb  = Qb  + nh;
    u16* Vb  = Kb  + nh;
    u16* Ob  = Vb  + nh;

    cvt4<<<(int)(nx / 4 / 256), 256, 0, stream>>>(x, xb, (int)(nx / 4));
    dim3 gw((unsigned)(nw / 4 / 256), 4);
    cvt4w<<<gw, 256, 0, stream>>>(Wq, Wk, Wv, Wo, wqb, wkb, wvb, wob, (int)(nw / 4));

    dim3 g1(BATCH * SEQ / 128, DM / 128, 3);        // 32 x 6 x 3
    qkv_mfma<<<g1, 256, 0, stream>>>(xb, wqb, wkb, wvb, Qb, Kb, Vb);

    dim3 g2(32, BATCH * NHEAD);                     // 32 x 24, 256 threads
    attn_mfma<<<g2, 256, 0, stream>>>(Qb, Kb, Vb, Ob);

    dim3 g3(BATCH * SEQ / 128, DM / 128);           // 32 x 6
    proj_mfma<<<g3, 256, 0, stream>>>(Ob, wob, out);
}

// Round 12
// 204.054 us; speedup vs baseline: 5.0997x; 1.0267x over previous
//
#include <hip/hip_runtime.h>
#include <math.h>

#define NHEAD 12
#define HD    64
#define SEQ   2048
#define BATCH 2
#define DM    768

typedef unsigned short u16;
typedef __attribute__((ext_vector_type(8))) short bf16x8;   // 8 bf16 = 4 VGPR
typedef __attribute__((ext_vector_type(8))) unsigned short u16x8;
typedef __attribute__((ext_vector_type(4))) float f32x4;

typedef const __attribute__((address_space(1))) unsigned int gu32;
typedef __attribute__((address_space(3))) unsigned int lu32;

__device__ __forceinline__ u16 f2bf(float f) {
    unsigned u = __builtin_bit_cast(unsigned, f);
    return (u16)((u + 0x7fffu + ((u >> 16) & 1u)) >> 16);    // RNE
}
__device__ __forceinline__ bf16x8 as_bf16x8(uint4 v) { return __builtin_bit_cast(bf16x8, v); }
__device__ __forceinline__ u16x8  as_u16x8(uint4 v)  { return __builtin_bit_cast(u16x8, v); }
__device__ __forceinline__ f32x4 mfma16(bf16x8 a, bf16x8 b, f32x4 c) {
    return __builtin_amdgcn_mfma_f32_16x16x32_bf16(a, b, c, 0, 0, 0);
}
// async global->LDS, 16B per lane; LDS dest = wave-uniform base + lane*16B
__device__ __forceinline__ void gl16(const u16* g, u16* l) {
    __builtin_amdgcn_global_load_lds((gu32*)g, (lu32*)l, 16, 0, 0);
}

// ---------------------------------------------------------------------------
// fp32 -> bf16 conversion
// ---------------------------------------------------------------------------
__global__ void cvt4(const float* __restrict__ s, u16* __restrict__ d, int n4) {
    int i = blockIdx.x * blockDim.x + threadIdx.x;
    if (i < n4) {
        float4 v = ((const float4*)s)[i];
        ushort4 o;
        o.x = f2bf(v.x); o.y = f2bf(v.y); o.z = f2bf(v.z); o.w = f2bf(v.w);
        ((ushort4*)d)[i] = o;
    }
}

__global__ void cvt4w(const float* __restrict__ s0, const float* __restrict__ s1,
                      const float* __restrict__ s2, const float* __restrict__ s3,
                      u16* __restrict__ d0, u16* __restrict__ d1,
                      u16* __restrict__ d2, u16* __restrict__ d3, int n4) {
    const float* s = blockIdx.y == 0 ? s0 : blockIdx.y == 1 ? s1 : blockIdx.y == 2 ? s2 : s3;
    u16*         d = blockIdx.y == 0 ? d0 : blockIdx.y == 1 ? d1 : blockIdx.y == 2 ? d2 : d3;
    int i = blockIdx.x * blockDim.x + threadIdx.x;
    if (i < n4) {
        float4 v = ((const float4*)s)[i];
        ushort4 o;
        o.x = f2bf(v.x); o.y = f2bf(v.y); o.z = f2bf(v.z); o.w = f2bf(v.w);
        ((ushort4*)d)[i] = o;
    }
}

// ---------------------------------------------------------------------------
// QKV projection v2: m97-style.  global_load_lds(16B) direct staging into
// linear double-buffered LDS [2][128][32]u16; chunk swizzle cg = c ^ (row&3)
// applied on SOURCE (stage) and READ (frags) — linear dest (rule #21).
// 2-phase: STAGE(t+1) -> ds_read+MFMA(t) -> barrier.  Q pre-scaled 0.125.
// ---------------------------------------------------------------------------
__global__ __launch_bounds__(256)
void qkv_mfma(const u16* __restrict__ X,
              const u16* __restrict__ Wq, const u16* __restrict__ Wk,
              const u16* __restrict__ Wv,
              u16* __restrict__ Q, u16* __restrict__ K, u16* __restrict__ V)
{
    const u16* W = blockIdx.z == 0 ? Wq : blockIdx.z == 1 ? Wk : Wv;
    u16*       Y = blockIdx.z == 0 ? Q  : blockIdx.z == 1 ? K  : V;
    const float osc = (blockIdx.z == 0) ? 0.125f : 1.0f;
    const int m0 = blockIdx.x * 128, n0 = blockIdx.y * 128;

    __shared__ __align__(16) u16 As[2][128 * 32];
    __shared__ __align__(16) u16 Bs[2][128 * 32];

    const int tid = threadIdx.x;
    const int w = tid >> 6, l = tid & 63, lg = l >> 4, lr = l & 15;
    const int wr = w >> 1, wc = w & 1;
    const int Lr = l >> 2;                 // row within 16-row block
    const int cg = (l & 3) ^ (Lr & 3);     // swizzled global chunk

    f32x4 acc[4][4];
    #pragma unroll
    for (int i = 0; i < 4; ++i)
        #pragma unroll
        for (int j = 0; j < 4; ++j) acc[i][j] = (f32x4){0.f, 0.f, 0.f, 0.f};

    auto STAGE = [&](int buf, int k0) {
        #pragma unroll
        for (int c = 0; c < 2; ++c) {
            const int rb = w * 32 + c * 16;          // wave-uniform block base
            const int r  = rb + Lr;
            gl16(X + (size_t)(m0 + r) * DM + k0 + cg * 8, &As[buf][rb * 32]);
            gl16(W + (size_t)(n0 + r) * DM + k0 + cg * 8, &Bs[buf][rb * 32]);
        }
    };

    int cur = 0;
    STAGE(0, 0);
    __syncthreads();

    const int ro = (lg ^ (lr & 3)) * 8;    // swizzled read chunk (u16 offset)
    for (int t = 0; t < 24; ++t) {
        if (t < 23) STAGE(cur ^ 1, (t + 1) * 32);
        bf16x8 af[4], bfr[4];
        #pragma unroll
        for (int i = 0; i < 4; ++i) {
            af[i]  = as_bf16x8(*(const uint4*)&As[cur][(wr * 64 + i * 16 + lr) * 32 + ro]);
            bfr[i] = as_bf16x8(*(const uint4*)&Bs[cur][(wc * 64 + i * 16 + lr) * 32 + ro]);
        }
        __builtin_amdgcn_s_setprio(1);
        #pragma unroll
        for (int i = 0; i < 4; ++i)
            #pragma unroll
            for (int j = 0; j < 4; ++j)
                acc[i][j] = mfma16(af[i], bfr[j], acc[i][j]);
        __builtin_amdgcn_s_setprio(0);
        __syncthreads();
        cur ^= 1;
    }

    #pragma unroll
    for (int i = 0; i < 4; ++i) {
        const int mb = m0 + wr * 64 + i * 16 + lg * 4;
        #pragma unroll
        for (int j = 0; j < 4; ++j) {
            const int n = n0 + wc * 64 + j * 16 + lr;
            const int h = n >> 6, dc = n & 63;
            #pragma unroll
            for (int r = 0; r < 4; ++r) {
                const int m = mb + r;
                const int b = m >> 11, s2 = m & 2047;
                Y[(((size_t)b * NHEAD + h) * SEQ + s2) * HD + dc] = f2bf(acc[i][j][r] * osc);
            }
        }
    }
}

// ---------------------------------------------------------------------------
// Flash attention v3 (verified R8): swapped QK^T, lane-local P, defer-max.
// UNCHANGED from R8.
// ---------------------------------------------------------------------------
__global__ __launch_bounds__(256)
void attn_mfma(const u16* __restrict__ Qg, const u16* __restrict__ Kg,
               const u16* __restrict__ Vg, u16* __restrict__ Og)
{
    const int q0 = (31 - blockIdx.x) * 64;     // longest-first
    const int bh = blockIdx.y;                 // 0..23
    const int kend = q0 >> 6;
    const size_t base = (size_t)bh * SEQ * HD;
    const u16* Qb = Qg + base;
    const u16* Kb = Kg + base;
    const u16* Vb = Vg + base;
    u16*       Ob = Og + base;

    __shared__ __align__(16) u16 Ks[64 * 64];      // [key][d], swizzled by key&7
    __shared__ __align__(16) u16 Vt[64 * 64];      // [d][key], swizzled by CS(d)

    const int tid = threadIdx.x;
    const int w = tid >> 6, l = tid & 63, lg = l >> 4, lr = l & 15;

    const int srow = w * 16 + (l >> 2);        // 0..63
    const int c0   = (l & 3) * 16;             // u16 col base

    const int qrow = q0 + w * 16 + lr;
    bf16x8 qf[2];
    #pragma unroll
    for (int kh = 0; kh < 2; ++kh)
        qf[kh] = as_bf16x8(*(const uint4*)(Qb + (size_t)qrow * HD + kh * 32 + lg * 8));

    float ms = -INFINITY, lsum = 0.f;          // per-lane: state of q-row lr
    f32x4 ov[4];                               // O[row=lg*4+r][d=dj*16+lr]
    #pragma unroll
    for (int dj = 0; dj < 4; ++dj) ov[dj] = (f32x4){0.f, 0.f, 0.f, 0.f};

    for (int kt = 0; kt <= kend; ++kt) {
        const int k0 = kt * 64;

        const u16* kp = Kb + (size_t)(k0 + srow) * HD + c0;
        const u16* vp = Vb + (size_t)(k0 + srow) * HD + c0;
        uint4 kq0 = *(const uint4*)(kp);
        uint4 kq1 = *(const uint4*)(kp + 8);
        uint4 vq0 = *(const uint4*)(vp);
        uint4 vq1 = *(const uint4*)(vp + 8);

        __syncthreads();
        {
            const int sw = (srow & 7) << 4;
            *(uint4*)&Ks[srow * 64 + (((c0 * 2) ^ sw) >> 1)]        = kq0;
            *(uint4*)&Ks[srow * 64 + ((((c0 + 8) * 2) ^ sw) >> 1)]  = kq1;
        }
        #pragma unroll
        for (int h = 0; h < 2; ++h) {
            u16x8 vv = as_u16x8(h ? vq1 : vq0);
            #pragma unroll
            for (int e = 0; e < 8; ++e) {
                const int d  = c0 + h * 8 + e;
                const int cs = (d & 7) ^ ((d >> 3) & 7);
                Vt[d * 64 + (((srow * 2) ^ (cs << 4)) >> 1)] = vv[e];
            }
        }
        __syncthreads();

        f32x4 sc[4];
        #pragma unroll
        for (int nj = 0; nj < 4; ++nj) sc[nj] = (f32x4){0.f, 0.f, 0.f, 0.f};
        __builtin_amdgcn_s_setprio(1);
        #pragma unroll
        for (int kh = 0; kh < 2; ++kh) {
            #pragma unroll
            for (int nj = 0; nj < 4; ++nj) {
                const int s  = nj * 16 + lr;
                const int cb = kh * 64 + lg * 16;
                bf16x8 kf = as_bf16x8(*(const uint4*)&Ks[s * 64 + ((cb ^ ((s & 7) << 4)) >> 1)]);
                sc[nj] = mfma16(kf, qf[kh], sc[nj]);
            }
        }
        __builtin_amdgcn_s_setprio(0);

        if (kt == kend) {
            #pragma unroll
            for (int nj = 0; nj < 4; ++nj)
                #pragma unroll
                for (int r = 0; r < 4; ++r) {
                    const int key = k0 + nj * 16 + lg * 4 + r;
                    if (key > qrow) sc[nj][r] = -INFINITY;
                }
        }

        float pm = sc[0][0];
        #pragma unroll
        for (int nj = 0; nj < 4; ++nj)
            #pragma unroll
            for (int r = 0; r < 4; ++r) pm = fmaxf(pm, sc[nj][r]);
        pm = fmaxf(pm, __shfl_xor(pm, 16));
        pm = fmaxf(pm, __shfl_xor(pm, 32));

        if (!__all(pm <= ms + 8.f)) {
            const float mn  = fmaxf(ms, pm);
            const float fac = __expf(ms - mn);
            ms = mn;
            lsum *= fac;
            const int fi = __builtin_bit_cast(int, fac);
            #pragma unroll
            for (int r = 0; r < 4; ++r) {
                const float fr = __builtin_bit_cast(float,
                    __builtin_amdgcn_ds_bpermute((lg * 4 + r) * 4, fi));
                #pragma unroll
                for (int dj = 0; dj < 4; ++dj) ov[dj][r] *= fr;
            }
        }

        float rs = 0.f;
        #pragma unroll
        for (int nj = 0; nj < 4; ++nj)
            #pragma unroll
            for (int r = 0; r < 4; ++r) {
                const float p = __expf(sc[nj][r] - ms);
                sc[nj][r] = p;
                rs += p;
            }
        rs += __shfl_xor(rs, 16);
        rs += __shfl_xor(rs, 32);
        lsum += rs;

        unsigned pw[4][2];
        #pragma unroll
        for (int nj = 0; nj < 4; ++nj) {
            asm("v_cvt_pk_bf16_f32 %0, %1, %2" : "=v"(pw[nj][0]) : "v"(sc[nj][0]), "v"(sc[nj][1]));
            asm("v_cvt_pk_bf16_f32 %0, %1, %2" : "=v"(pw[nj][1]) : "v"(sc[nj][2]), "v"(sc[nj][3]));
        }

        __builtin_amdgcn_s_setprio(1);
        #pragma unroll
        for (int ks = 0; ks < 2; ++ks) {
            uint4 pa4;
            pa4.x = pw[2 * ks][0]; pa4.y = pw[2 * ks][1];
            pa4.z = pw[2 * ks + 1][0]; pa4.w = pw[2 * ks + 1][1];
            const bf16x8 pa = as_bf16x8(pa4);
            const int b0 = 64 * ks + 8 * lg;
            #pragma unroll
            for (int dj = 0; dj < 4; ++dj) {
                const int d  = dj * 16 + lr;
                const int cs = (d & 7) ^ ((d >> 3) & 7);
                const uint2 v0 = *(const uint2*)&Vt[d * 64 + ((b0 ^ (cs << 4)) >> 1)];
                const uint2 v1 = *(const uint2*)&Vt[d * 64 + (((b0 + 32) ^ (cs << 4)) >> 1)];
                uint4 vv; vv.x = v0.x; vv.y = v0.y; vv.z = v1.x; vv.w = v1.y;
                ov[dj] = mfma16(pa, as_bf16x8(vv), ov[dj]);
            }
        }
        __builtin_amdgcn_s_setprio(0);
    }

    const int li = __builtin_bit_cast(int, lsum);
    #pragma unroll
    for (int r = 0; r < 4; ++r) {
        const float lrow = __builtin_bit_cast(float,
            __builtin_amdgcn_ds_bpermute((lg * 4 + r) * 4, li));
        const float inv = 1.0f / lrow;
        const int row = q0 + w * 16 + lg * 4 + r;
        #pragma unroll
        for (int dj = 0; dj < 4; ++dj)
            Ob[(size_t)row * HD + dj * 16 + lr] = f2bf(ov[dj][r] * inv);
    }
}

// ---------------------------------------------------------------------------
// Output projection v2: same m97-style staging; A gathered from [B,H,S,hd]
// via the per-lane global address (gload_lds source is per-lane).
// ---------------------------------------------------------------------------
__global__ __launch_bounds__(256)
void proj_mfma(const u16* __restrict__ O, const u16* __restrict__ Wo,
               float* __restrict__ out)
{
    const int m0 = blockIdx.x * 128, n0 = blockIdx.y * 128;

    __shared__ __align__(16) u16 As[2][128 * 32];
    __shared__ __align__(16) u16 Bs[2][128 * 32];

    const int tid = threadIdx.x;
    const int w = tid >> 6, l = tid & 63, lg = l >> 4, lr = l & 15;
    const int wr = w >> 1, wc = w & 1;
    const int Lr = l >> 2;
    const int cg = (l & 3) ^ (Lr & 3);

    f32x4 acc[4][4];
    #pragma unroll
    for (int i = 0; i < 4; ++i)
        #pragma unroll
        for (int j = 0; j < 4; ++j) acc[i][j] = (f32x4){0.f, 0.f, 0.f, 0.f};

    auto STAGE = [&](int buf, int k0) {
        #pragma unroll
        for (int c = 0; c < 2; ++c) {
            const int rb = w * 32 + c * 16;
            const int r  = rb + Lr;
            {   // A gather from [B,H,S,hd]
                const int m = m0 + r;
                const int b = m >> 11, s2 = m & 2047;
                const int k = k0 + cg * 8;
                const int h = k >> 6, dk = k & 63;
                gl16(O + (((size_t)b * NHEAD + h) * SEQ + s2) * HD + dk, &As[buf][rb * 32]);
            }
            gl16(Wo + (size_t)(n0 + r) * DM + k0 + cg * 8, &Bs[buf][rb * 32]);
        }
    };

    int cur = 0;
    STAGE(0, 0);
    __syncthreads();

    const int ro = (lg ^ (lr & 3)) * 8;
    for (int t = 0; t < 24; ++t) {
        if (t < 23) STAGE(cur ^ 1, (t + 1) * 32);
        bf16x8 af[4], bfr[4];
        #pragma unroll
        for (int i = 0; i < 4; ++i) {
            af[i]  = as_bf16x8(*(const uint4*)&As[cur][(wr * 64 + i * 16 + lr) * 32 + ro]);
            bfr[i] = as_bf16x8(*(const uint4*)&Bs[cur][(wc * 64 + i * 16 + lr) * 32 + ro]);
        }
        __builtin_amdgcn_s_setprio(1);
        #pragma unroll
        for (int i = 0; i < 4; ++i)
            #pragma unroll
            for (int j = 0; j < 4; ++j)
                acc[i][j] = mfma16(af[i], bfr[j], acc[i][j]);
        __builtin_amdgcn_s_setprio(0);
        __syncthreads();
        cur ^= 1;
    }

    #pragma unroll
    for (int i = 0; i < 4; ++i) {
        const int mb = m0 + wr * 64 + i * 16 + lg * 4;
        #pragma unroll
        for (int j = 0; j < 4; ++j) {
            const int n = n0 + wc * 64 + j * 16 + lr;
            #pragma unroll
            for (int r = 0; r < 4; ++r)
                out[(size_t)(mb + r) * DM + n] = acc[i][j][r];
        }
    }
}

// ---------------------------------------------------------------------------
extern "C" void kernel_launch(void* const* d_in, const int* in_sizes, int n_in,
                              void* d_out, int out_size, void* d_ws, size_t ws_size,
                              hipStream_t stream)
{
    const float* x  = (const float*)d_in[0];
    const float* Wq = (const float*)d_in[1];
    const float* Wk = (const float*)d_in[2];
    const float* Wv = (const float*)d_in[3];
    const float* Wo = (const float*)d_in[4];
    float* out = (float*)d_out;

    const size_t nx = (size_t)BATCH * SEQ * DM;          // 3,145,728
    const size_t nw = (size_t)DM * DM;                   //   589,824
    const size_t nh = (size_t)BATCH * NHEAD * SEQ * HD;  // == nx

    u16* xb  = (u16*)d_ws;
    u16* wqb = xb  + nx;
    u16* wkb = wqb + nw;
    u16* wvb = wkb + nw;
    u16* wob = wvb + nw;
    u16* Qb  = wob + nw;
    u16* Kb  = Qb  + nh;
    u16* Vb  = Kb  + nh;
    u16* Ob  = Vb  + nh;

    cvt4<<<(int)(nx / 4 / 256), 256, 0, stream>>>(x, xb, (int)(nx / 4));
    dim3 gw((unsigned)(nw / 4 / 256), 4);
    cvt4w<<<gw, 256, 0, stream>>>(Wq, Wk, Wv, Wo, wqb, wkb, wvb, wob, (int)(nw / 4));

    dim3 g1(BATCH * SEQ / 128, DM / 128, 3);        // 32 x 6 x 3
    qkv_mfma<<<g1, 256, 0, stream>>>(xb, wqb, wkb, wvb, Qb, Kb, Vb);

    dim3 g2(32, BATCH * NHEAD);                     // 32 x 24, 256 threads
    attn_mfma<<<g2, 256, 0, stream>>>(Qb, Kb, Vb, Ob);

    dim3 g3(BATCH * SEQ / 128, DM / 128);           // 32 x 6
    proj_mfma<<<g3, 256, 0, stream>>>(Ob, wob, out);
}